// Round 3
// baseline (432.212 us; speedup 1.0000x reference)
//
#include <hip/hip_runtime.h>

// LIF neuron forward: x [B=16, C=64, T=16, H=64, W=64] f32, decay (1,) f32.
//   mem   = mem_old * sigmoid(decay) * (1 - spike) + x_t
//   spike = (mem > 0.5) ? 1 : 0
// out = spikes (clip to [0,1] is identity on {0,1}).
//
// Round 2 changes:
//  - 8-deep ring-buffer software pipeline (xv[8] = 32 VGPRs instead of
//    xv[16] = 64) -> target <=64 VGPRs -> 8 waves/SIMD (100% occupancy).
//  - Fully-resident grid: 2048 blocks x 256 thr = 8 blocks/CU on 256 CUs,
//    each thread does 2 columns grid-stride -> no dispatch-round tail;
//    column 1's loads overlap column 0's compute/store drain.
//  - Nontemporal load/store kept (touch-once streams, 268 MB >> 32 MB L2).

#define T_STEPS 16
#define HW      4096            // H*W
#define BC      1024            // B*C
#define NCOL    (BC * (HW / 4)) // 1,048,576 float4 columns total
#define NTHREAD (NCOL / 2)      // 524,288 threads, 2 columns each
#define PIPE    8

typedef float f4 __attribute__((ext_vector_type(4)));

__global__ __launch_bounds__(256, 8) void
lif_fwd_kernel(const float* __restrict__ x,
               const float* __restrict__ decay,
               float* __restrict__ out) {
    const unsigned tid = blockIdx.x * blockDim.x + threadIdx.x;  // [0, NTHREAD)

    const float d  = decay[0];
    const float ds = 1.0f / (1.0f + expf(-d));

#pragma unroll
    for (int col_pass = 0; col_pass < 2; ++col_pass) {
        const unsigned col  = tid + (unsigned)col_pass * NTHREAD; // [0, NCOL)
        const unsigned bc   = col >> 10;                          // / (HW/4)
        const unsigned s4   = col & ((HW / 4) - 1);
        const unsigned base = bc * (T_STEPS * HW) + s4 * 4;       // element offset

        // Prime the 8-deep pipeline.
        f4 xv[PIPE];
#pragma unroll
        for (int t = 0; t < PIPE; ++t) {
            xv[t] = __builtin_nontemporal_load(
                reinterpret_cast<const f4*>(x + base + (unsigned)t * HW));
        }

        float mx = 0.f, my = 0.f, mz = 0.f, mw = 0.f;
        float sx = 0.f, sy = 0.f, sz = 0.f, sw = 0.f;

#pragma unroll
        for (int t = 0; t < T_STEPS; ++t) {
            const f4 v = xv[t & (PIPE - 1)];
            if (t + PIPE < T_STEPS) {
                xv[t & (PIPE - 1)] = __builtin_nontemporal_load(
                    reinterpret_cast<const f4*>(x + base + (unsigned)(t + PIPE) * HW));
            }

            // Un-fused fp32 ops to mirror XLA's separate mul/mul/add rounding.
            mx = __fadd_rn(__fmul_rn(__fmul_rn(mx, ds), 1.0f - sx), v.x);
            my = __fadd_rn(__fmul_rn(__fmul_rn(my, ds), 1.0f - sy), v.y);
            mz = __fadd_rn(__fmul_rn(__fmul_rn(mz, ds), 1.0f - sz), v.z);
            mw = __fadd_rn(__fmul_rn(__fmul_rn(mw, ds), 1.0f - sw), v.w);

            sx = (mx > 0.5f) ? 1.0f : 0.0f;
            sy = (my > 0.5f) ? 1.0f : 0.0f;
            sz = (mz > 0.5f) ? 1.0f : 0.0f;
            sw = (mw > 0.5f) ? 1.0f : 0.0f;

            f4 ov;
            ov.x = sx; ov.y = sy; ov.z = sz; ov.w = sw;
            __builtin_nontemporal_store(ov,
                reinterpret_cast<f4*>(out + base + (unsigned)t * HW));
        }
    }
}

extern "C" void kernel_launch(void* const* d_in, const int* in_sizes, int n_in,
                              void* d_out, int out_size, void* d_ws, size_t ws_size,
                              hipStream_t stream) {
    const float* x     = (const float*)d_in[0];
    const float* decay = (const float*)d_in[1];
    float*       out   = (float*)d_out;

    const int block = 256;
    const int grid  = NTHREAD / block;   // 2048 blocks = 8 resident blocks/CU
    lif_fwd_kernel<<<grid, block, 0, stream>>>(x, decay, out);
}